// Round 8
// baseline (81.256 us; speedup 1.0000x reference)
//
#include <hip/hip_runtime.h>
#include <hip/hip_bf16.h>
#include <stdint.h>

#define N_IN 195
#define N_OUT 778
#define D_IN 256
#define D_OUTC 128
#define NS 9
#define KTOT 2304          // NS * D_IN
#define MM 49792           // 64 * 778 = 389 * 128, no tail
#define BM 128
#define BK 64
#define NWG 389
#define POOL_BLOCKS 12448  // MM / 4
#define BF_BLOCKS 144      // 72 k32-blocks * 8 colfrags * 64 lanes / 256 thr

using short8  = __attribute__((ext_vector_type(8))) short;
using short4v = __attribute__((ext_vector_type(4))) short;
using f32x4   = __attribute__((ext_vector_type(4))) float;

__device__ __forceinline__ void gload16(const void* g, void* l) {
  __builtin_amdgcn_global_load_lds(
      (const __attribute__((address_space(1))) uint32_t*)g,
      (__attribute__((address_space(3))) uint32_t*)l, 16, 0, 0);
}

__device__ __forceinline__ unsigned short f2bf(float f) {  // RNE
  uint32_t u = __float_as_uint(f);
  return (unsigned short)((u + 0x7FFFu + ((u >> 16) & 1u)) >> 16);
}

// ---------------- kernel 1: pool + bf16 convert, fused W fragment-pack ------
// Bfrag layout: [(kb)(72)][(cf)(8)][(lane)(64)][8 elems] of bf16;
//   element = W[kb*32 + (lane>>4)*8 + e][cf*16 + (lane&15)]
// so one wave's B-fragment for mfma_16x16x32 is ONE coalesced 1KB load.
__global__ __launch_bounds__(256) void prep_kernel(
    const float* __restrict__ x, const int* __restrict__ col,
    const float* __restrict__ value, const float* __restrict__ W,
    unsigned short* __restrict__ pooled, unsigned short* __restrict__ Bfrag) {
  int bid = blockIdx.x;
  if (bid < POOL_BLOCKS) {
    int m = bid * 4 + (threadIdx.x >> 6);
    int lane = threadIdx.x & 63;
    int b = (unsigned)m / N_OUT;
    int n = m - b * N_OUT;
    int j = 3 * n;
    int c0 = col[j], c1 = col[j + 1], c2 = col[j + 2];
    float v0 = value[j], v1 = value[j + 1], v2 = value[j + 2];
    const float4* x0 = (const float4*)(x + ((size_t)b * N_IN + c0) * D_IN);
    const float4* x1 = (const float4*)(x + ((size_t)b * N_IN + c1) * D_IN);
    const float4* x2 = (const float4*)(x + ((size_t)b * N_IN + c2) * D_IN);
    float4 a0 = x0[lane], a1 = x1[lane], a2 = x2[lane];
    short4v pk;
    pk[0] = (short)f2bf(v0 * a0.x + v1 * a1.x + v2 * a2.x);
    pk[1] = (short)f2bf(v0 * a0.y + v1 * a1.y + v2 * a2.y);
    pk[2] = (short)f2bf(v0 * a0.z + v1 * a1.z + v2 * a2.z);
    pk[3] = (short)f2bf(v0 * a0.w + v1 * a1.w + v2 * a2.w);
    ((short4v*)(pooled + (size_t)m * D_IN))[lane] = pk;
  } else {
    int idx = (bid - POOL_BLOCKS) * 256 + threadIdx.x;  // over 72*8*64
    int lane = idx & 63;
    int cf = (idx >> 6) & 7;
    int kb = idx >> 9;                 // 0..71
    int kbase = kb * 32 + (lane >> 4) * 8;
    int o = cf * 16 + (lane & 15);
    short8 pk;
    #pragma unroll
    for (int e = 0; e < 8; ++e)
      pk[e] = (short)f2bf(W[(size_t)(kbase + e) * D_OUTC + o]);
    *(short8*)(Bfrag + (size_t)idx * 8) = pk;
  }
}

// ---------------- kernel 2: gather-GEMM, A-only LDS, B fragment-direct ------
// 512 thr = 8 waves; wave tile 32x64 (2x4 frags of 16x16), 16x16x32 MFMA.
// A: 2x16KB LDS dbuf (gload_lds, XOR swizzle). B: coalesced 1KB reg loads
// from Bfrag (L1/L2-resident, 576KB total).
__global__ __launch_bounds__(512, 4) void gemm_kernel(
    const unsigned short* __restrict__ pooled,   // bf16 bits [MM][256]
    const unsigned short* __restrict__ Bfrag,    // bf16 bits [72][8][64][8]
    const int* __restrict__ indices,
    const float* __restrict__ bias,
    float* __restrict__ out) {
  __shared__ unsigned short Asm[2][BM * BK];     // 2 x 16 KB only

  const int tid = threadIdx.x;
  const int wave = tid >> 6, lane = tid & 63;
  const int wr = wave >> 1, wc = wave & 1;       // 4x2 waves of 32x64

  // XCD-aware bijective swizzle (NWG=389: q8=48, r8=5)
  const int xcd = blockIdx.x & 7, loc = blockIdx.x >> 3;
  const int q8 = NWG >> 3, r8 = NWG & 7;
  const int wg = (xcd < r8 ? xcd * (q8 + 1) : r8 * (q8 + 1) + (xcd - r8) * q8) + loc;
  const int bm = wg * BM;

  // A staging geometry: 2 instrs; instr i covers rows r = i*64 + (tid>>3),
  // 8 threads/row, chunk (tid&7) of 8x16B = 128B row, XOR source swizzle.
  const int srow = tid >> 3;                     // 0..63
  const int sc = ((tid & 7) ^ (srow & 7)) * 8;   // swizzled source chunk (elems)
  int nn[2]; size_t gb[2];
  #pragma unroll
  for (int i = 0; i < 2; ++i) {
    int r = i * 64 + srow;                       // 0..127
    int m = bm + r;
    int b = (unsigned)m / N_OUT;
    nn[i] = m - b * N_OUT;
    gb[i] = (size_t)b * N_OUT;
  }
  char* AsmB = (char*)&Asm[0][0];

  // B fragment base for this wave's column half (wc): cf = wc*4 + j
  const unsigned short* bfbase = Bfrag + ((size_t)wc * 4 * 64 + lane) * 8;

  // spiral gather indices, current + next
  int gc[2], gn[2];
  #pragma unroll
  for (int i = 0; i < 2; ++i) gc[i] = indices[nn[i] * NS + 0];

  f32x4 acc[2][4];
  #pragma unroll
  for (int i = 0; i < 2; ++i)
    #pragma unroll
    for (int j = 0; j < 4; ++j) acc[i][j] = f32x4{0.f, 0.f, 0.f, 0.f};

  // stage A for phase (s, q) into buffer buf
  auto stageA = [&](int buf, int s, int q, const int* g) {
    const int bofs = buf * 16384;
    #pragma unroll
    for (int i = 0; i < 2; ++i) {
      const unsigned short* srcA =
          pooled + (((gb[i] + (size_t)g[i]) << 8) + q * 64 + sc);
      gload16(srcA, AsmB + bofs + i * 8192 + tid * 16);
    }
  };

  // load B fragments for phase p (all 8: 2 k-halves x 4 col-frags)
  auto loadB = [&](short8 bf[2][4], int p) {
    #pragma unroll
    for (int h = 0; h < 2; ++h) {
      const unsigned short* kb = bfbase + (size_t)(p * 2 + h) * 8 * 64 * 8;
      #pragma unroll
      for (int j = 0; j < 4; ++j)
        bf[h][j] = *(const short8*)(kb + (size_t)j * 64 * 8);
    }
  };

  auto compute = [&](int buf, const short8 bf[2][4]) {
    const char* Ab = AsmB + buf * 16384;
    #pragma unroll
    for (int h = 0; h < 2; ++h) {
      short8 af[2];
      const int cb = h * 64 + (lane >> 4) * 16;  // byte col within 128B row
      #pragma unroll
      for (int i = 0; i < 2; ++i) {
        int r = wr * 32 + i * 16 + (lane & 15);
        af[i] = *(const short8*)(Ab + r * 128 + (cb ^ ((r & 7) << 4)));
      }
      __builtin_amdgcn_s_setprio(1);
      #pragma unroll
      for (int i = 0; i < 2; ++i)
        #pragma unroll
        for (int j = 0; j < 4; ++j)
          acc[i][j] = __builtin_amdgcn_mfma_f32_16x16x32_bf16(
              af[i], bf[h][j], acc[i][j], 0, 0, 0);
      __builtin_amdgcn_s_setprio(0);
    }
  };

  // ---- pipeline over 36 phases (9 spirals x 4 quarters), R7-proven ---------
  stageA(0, 0, 0, gc);
  __syncthreads();

  for (int s = 0; s < NS; ++s) {
    #pragma unroll
    for (int q = 0; q < 4; ++q) {
      int p = s * 4 + q;
      int buf = p & 1;
      short8 bf[2][4];
      loadB(bf, p);      // issued BEFORE next-phase staging: compute's waits
                         // on bf don't drain the A prefetch
      if (q == 0 && s < NS - 1) {
        #pragma unroll
        for (int i = 0; i < 2; ++i) gn[i] = indices[nn[i] * NS + s + 1];
      }
      if (q < 3)            stageA(buf ^ 1, s, q + 1, gc);
      else if (s < NS - 1)  stageA(buf ^ 1, s + 1, 0, gn);
      compute(buf, bf);
      __syncthreads();   // drains vmcnt(0); cross-block TLP hides the stall
    }
    #pragma unroll
    for (int i = 0; i < 2; ++i) gc[i] = gn[i];
  }

  // ---- epilogue: bias + relu ----
  #pragma unroll
  for (int j = 0; j < 4; ++j) {
    int colo = wc * 64 + j * 16 + (lane & 15);
    float bo = bias[colo];
    #pragma unroll
    for (int i = 0; i < 2; ++i) {
      int rb = bm + wr * 32 + i * 16 + (lane >> 4) * 4;
      #pragma unroll
      for (int q = 0; q < 4; ++q) {
        int row = rb + q;
        out[(size_t)row * D_OUTC + colo] = fmaxf(acc[i][j][q] + bo, 0.f);
      }
    }
  }
}

extern "C" void kernel_launch(void* const* d_in, const int* in_sizes, int n_in,
                              void* d_out, int out_size, void* d_ws, size_t ws_size,
                              hipStream_t stream) {
  const float* x       = (const float*)d_in[0];
  // d_in[1] = row (unused: structure is repeat(arange(N_out),3))
  const int*   col     = (const int*)d_in[2];
  const float* value   = (const float*)d_in[3];
  const int*   indices = (const int*)d_in[4];
  const float* W       = (const float*)d_in[5];
  const float* bias    = (const float*)d_in[6];
  float* out           = (float*)d_out;

  unsigned short* pooled = (unsigned short*)d_ws;
  unsigned short* Bfrag = (unsigned short*)((char*)d_ws + (size_t)MM * D_IN * 2);

  prep_kernel<<<POOL_BLOCKS + BF_BLOCKS, 256, 0, stream>>>(x, col, value, W,
                                                           pooled, Bfrag);
  gemm_kernel<<<NWG, 512, 0, stream>>>(pooled, Bfrag, indices, bias, out);
}

// Round 9
// 73.825 us; speedup vs baseline: 1.1007x; 1.1007x over previous
//
#include <hip/hip_runtime.h>
#include <hip/hip_bf16.h>
#include <stdint.h>

#define N_IN 195
#define N_OUT 778
#define D_IN 256
#define D_OUTC 128
#define NS 9
#define KTOT 2304          // NS * D_IN
#define MM 49792           // 64 * 778
#define BM 256
#define BK 64
#define NWG 195            // ceil(MM/256); last tile half-padded
#define XE 3194880         // x elems = 64*195*256
#define XCVT_BLOCKS 1560   // XE / (256*8)
#define POOL_BLOCKS 6224   // MM / 8
#define WT_BLOCKS 1152     // 128*2304/256

using short8  = __attribute__((ext_vector_type(8))) short;
using f32x4   = __attribute__((ext_vector_type(4))) float;

__device__ __forceinline__ void gload16(const void* g, void* l) {
  __builtin_amdgcn_global_load_lds(
      (const __attribute__((address_space(1))) uint32_t*)g,
      (__attribute__((address_space(3))) uint32_t*)l, 16, 0, 0);
}

__device__ __forceinline__ unsigned short f2bf(float f) {  // RNE
  uint32_t u = __float_as_uint(f);
  return (unsigned short)((u + 0x7FFFu + ((u >> 16) & 1u)) >> 16);
}
__device__ __forceinline__ float bf2f(unsigned short s) {
  return __uint_as_float(((uint32_t)s) << 16);
}

// ---------------- kernel 0: x -> bf16 ---------------------------------------
__global__ __launch_bounds__(256) void xcvt_kernel(
    const float* __restrict__ x, unsigned short* __restrict__ xh) {
  int i = (blockIdx.x * 256 + threadIdx.x) * 8;
  float4 a = *(const float4*)(x + i);
  float4 b = *(const float4*)(x + i + 4);
  short8 pk;
  pk[0] = (short)f2bf(a.x); pk[1] = (short)f2bf(a.y);
  pk[2] = (short)f2bf(a.z); pk[3] = (short)f2bf(a.w);
  pk[4] = (short)f2bf(b.x); pk[5] = (short)f2bf(b.y);
  pk[6] = (short)f2bf(b.z); pk[7] = (short)f2bf(b.w);
  *(short8*)(xh + i) = pk;
}

// ---------------- kernel 1: pool (bf16 gather) + W transpose ----------------
__global__ __launch_bounds__(256) void prep_kernel(
    const unsigned short* __restrict__ xh, const int* __restrict__ col,
    const float* __restrict__ value, const float* __restrict__ W,
    unsigned short* __restrict__ pooled, unsigned short* __restrict__ Wt) {
  int bid = blockIdx.x;
  if (bid < POOL_BLOCKS) {
    int m = bid * 8 + (threadIdx.x >> 5);        // 8 rows/block, 32 thr/row
    int t = threadIdx.x & 31;                    // 8 elems each
    int b = (unsigned)m / N_OUT;
    int n = m - b * N_OUT;
    int j = 3 * n;
    int c0 = col[j], c1 = col[j + 1], c2 = col[j + 2];
    float v0 = value[j], v1 = value[j + 1], v2 = value[j + 2];
    const short8* x0 = (const short8*)(xh + ((size_t)b * N_IN + c0) * D_IN);
    const short8* x1 = (const short8*)(xh + ((size_t)b * N_IN + c1) * D_IN);
    const short8* x2 = (const short8*)(xh + ((size_t)b * N_IN + c2) * D_IN);
    short8 a0 = x0[t], a1 = x1[t], a2 = x2[t];
    short8 pk;
    #pragma unroll
    for (int e = 0; e < 8; ++e) {
      float f = v0 * bf2f((unsigned short)a0[e]) +
                v1 * bf2f((unsigned short)a1[e]) +
                v2 * bf2f((unsigned short)a2[e]);
      pk[e] = (short)f2bf(f);
    }
    ((short8*)(pooled + (size_t)m * D_IN))[t] = pk;
  } else {
    int idx = (bid - POOL_BLOCKS) * 256 + threadIdx.x;  // over 128*2304
    int o = idx / KTOT, k = idx - o * KTOT;
    Wt[idx] = f2bf(W[(size_t)k * D_OUTC + o]);
  }
}

// ---------------- kernel 2: gather-GEMM, BM=256, 8 waves of 64x64 -----------
// 512 thr = 8 waves (4 row-groups x 2 col-groups); wave tile 64x64
// (4x4 frags of 16x16), 16x16x32 MFMA. LDS: A 2x32KB + B 2x16KB = 96KB.
__global__ __launch_bounds__(512, 2) void gemm_kernel(
    const unsigned short* __restrict__ pooled,   // bf16 bits [MM][256]
    const unsigned short* __restrict__ Wt,       // bf16 bits [128][2304]
    const int* __restrict__ indices,
    const float* __restrict__ bias,
    float* __restrict__ out) {
  __shared__ unsigned short Asm[2][BM * BK];     // 2 x 32 KB
  __shared__ unsigned short Bsm[2][D_OUTC * BK]; // 2 x 16 KB

  const int tid = threadIdx.x;
  const int wave = tid >> 6, lane = tid & 63;
  const int wr = wave >> 1, wc = wave & 1;       // 4x2 waves of 64x64

  // XCD-aware bijective swizzle (NWG=195: q8=24, r8=3)
  const int xcd = blockIdx.x & 7, loc = blockIdx.x >> 3;
  const int q8 = NWG >> 3, r8 = NWG & 7;
  const int wg = (xcd < r8 ? xcd * (q8 + 1) : r8 * (q8 + 1) + (xcd - r8) * q8) + loc;
  const int bm = wg * BM;

  // staging geometry: srow = tid>>3 (0..63), chunk = tid&7 of 8x16B/row.
  // A: 4 instrs, rows r = i*64+srow; B: 2 instrs, rows o = i*64+srow.
  const int srow = tid >> 3;
  const int sc = ((tid & 7) ^ (srow & 7)) * 8;   // XOR-swizzled source chunk
  int nn[4]; size_t gb[4];
  #pragma unroll
  for (int i = 0; i < 4; ++i) {
    int r = i * 64 + srow;                       // 0..255
    int m = bm + r; if (m >= MM) m = MM - 1;     // tail clamp (stores guarded)
    int b = (unsigned)m / N_OUT;
    nn[i] = m - b * N_OUT;
    gb[i] = (size_t)b * N_OUT;
  }
  const unsigned short* wtrow[2];
  #pragma unroll
  for (int i = 0; i < 2; ++i)
    wtrow[i] = Wt + (size_t)(i * 64 + srow) * KTOT + sc;
  char* AsmB = (char*)&Asm[0][0];
  char* BsmB = (char*)&Bsm[0][0];

  // spiral gather indices, current + next
  int gc[4], gn[4];
  #pragma unroll
  for (int i = 0; i < 4; ++i) gc[i] = indices[nn[i] * NS + 0];

  f32x4 acc[4][4];
  #pragma unroll
  for (int i = 0; i < 4; ++i)
    #pragma unroll
    for (int j = 0; j < 4; ++j) acc[i][j] = f32x4{0.f, 0.f, 0.f, 0.f};

  auto stage = [&](int buf, int s, int q, const int* g) {
    const int kq = s * 256 + q * 64;
    #pragma unroll
    for (int i = 0; i < 4; ++i) {
      const unsigned short* srcA =
          pooled + (((gb[i] + (size_t)g[i]) << 8) + q * 64 + sc);
      gload16(srcA, AsmB + buf * 32768 + i * 8192 + tid * 16);
    }
    #pragma unroll
    for (int i = 0; i < 2; ++i)
      gload16(wtrow[i] + kq, BsmB + buf * 16384 + i * 8192 + tid * 16);
  };

  auto compute = [&](int buf) {
    const char* Ab = AsmB + buf * 32768;
    const char* Bb = BsmB + buf * 16384;
    #pragma unroll
    for (int h = 0; h < 2; ++h) {
      short8 af[4], bf[4];
      const int cb = h * 64 + (lane >> 4) * 16;  // byte col within 128B row
      #pragma unroll
      for (int i = 0; i < 4; ++i) {
        int r = wr * 64 + i * 16 + (lane & 15);
        af[i] = *(const short8*)(Ab + r * 128 + (cb ^ ((r & 7) << 4)));
      }
      #pragma unroll
      for (int j = 0; j < 4; ++j) {
        int o = wc * 64 + j * 16 + (lane & 15);
        bf[j] = *(const short8*)(Bb + o * 128 + (cb ^ ((o & 7) << 4)));
      }
      __builtin_amdgcn_s_setprio(1);
      #pragma unroll
      for (int i = 0; i < 4; ++i)
        #pragma unroll
        for (int j = 0; j < 4; ++j)
          acc[i][j] = __builtin_amdgcn_mfma_f32_16x16x32_bf16(
              af[i], bf[j], acc[i][j], 0, 0, 0);
      __builtin_amdgcn_s_setprio(0);
    }
  };

  // ---- pipeline over 36 phases (9 spirals x 4 quarters), R7-proven ---------
  stage(0, 0, 0, gc);
  __syncthreads();

  for (int s = 0; s < NS; ++s) {
    #pragma unroll
    for (int q = 0; q < 4; ++q) {
      int buf = (s * 4 + q) & 1;
      if (q == 0 && s < NS - 1) {
        #pragma unroll
        for (int i = 0; i < 4; ++i) gn[i] = indices[nn[i] * NS + s + 1];
      }
      if (q < 3)            stage(buf ^ 1, s, q + 1, gc);
      else if (s < NS - 1)  stage(buf ^ 1, s + 1, 0, gn);
      compute(buf);
      __syncthreads();   // drains vmcnt(0); buffer swap safe for all waves
    }
    #pragma unroll
    for (int i = 0; i < 4; ++i) gc[i] = gn[i];
  }

  // ---- epilogue: bias + relu (guard tail rows) ----
  #pragma unroll
  for (int j = 0; j < 4; ++j) {
    int colo = wc * 64 + j * 16 + (lane & 15);
    float bo = bias[colo];
    #pragma unroll
    for (int i = 0; i < 4; ++i) {
      int rb = bm + wr * 64 + i * 16 + (lane >> 4) * 4;
      #pragma unroll
      for (int q = 0; q < 4; ++q) {
        int row = rb + q;
        if (row < MM) out[(size_t)row * D_OUTC + colo] = fmaxf(acc[i][j][q] + bo, 0.f);
      }
    }
  }
}

extern "C" void kernel_launch(void* const* d_in, const int* in_sizes, int n_in,
                              void* d_out, int out_size, void* d_ws, size_t ws_size,
                              hipStream_t stream) {
  const float* x       = (const float*)d_in[0];
  // d_in[1] = row (unused: structure is repeat(arange(N_out),3))
  const int*   col     = (const int*)d_in[2];
  const float* value   = (const float*)d_in[3];
  const int*   indices = (const int*)d_in[4];
  const float* W       = (const float*)d_in[5];
  const float* bias    = (const float*)d_in[6];
  float* out           = (float*)d_out;

  unsigned short* pooled = (unsigned short*)d_ws;
  unsigned short* Wt  = (unsigned short*)((char*)d_ws + (size_t)MM * D_IN * 2);
  unsigned short* xh  = (unsigned short*)((char*)d_ws + (size_t)MM * D_IN * 2
                                          + (size_t)D_OUTC * KTOT * 2);

  xcvt_kernel<<<XCVT_BLOCKS, 256, 0, stream>>>(x, xh);
  prep_kernel<<<POOL_BLOCKS + WT_BLOCKS, 256, 0, stream>>>(xh, col, value, W,
                                                           pooled, Wt);
  gemm_kernel<<<NWG, 512, 0, stream>>>(pooled, Wt, indices, bias, out);
}

// Round 10
// 71.804 us; speedup vs baseline: 1.1316x; 1.0281x over previous
//
#include <hip/hip_runtime.h>
#include <hip/hip_bf16.h>
#include <stdint.h>

#define N_IN 195
#define N_OUT 778
#define D_IN 256
#define D_OUTC 128
#define NS 9
#define KTOT 2304          // NS * D_IN
#define MM 49792           // 64 * 778
#define BM 256
#define BK 64
#define NWG 195            // ceil(MM/256); last tile half-padded
#define XE 3194880         // x elems = 64*195*256
#define XCVT_BLOCKS 1560   // XE / (256*8)
#define POOL_BLOCKS 6224   // MM / 8
#define WT_BLOCKS 1152     // 128*2304/256

using short8  = __attribute__((ext_vector_type(8))) short;
using f32x4   = __attribute__((ext_vector_type(4))) float;

__device__ __forceinline__ void gload16(const void* g, void* l) {
  __builtin_amdgcn_global_load_lds(
      (const __attribute__((address_space(1))) uint32_t*)g,
      (__attribute__((address_space(3))) uint32_t*)l, 16, 0, 0);
}

__device__ __forceinline__ unsigned short f2bf(float f) {  // RNE
  uint32_t u = __float_as_uint(f);
  return (unsigned short)((u + 0x7FFFu + ((u >> 16) & 1u)) >> 16);
}
__device__ __forceinline__ float bf2f(unsigned short s) {
  return __uint_as_float(((uint32_t)s) << 16);
}

// ---------------- kernel 0: x -> bf16 ---------------------------------------
__global__ __launch_bounds__(256) void xcvt_kernel(
    const float* __restrict__ x, unsigned short* __restrict__ xh) {
  int i = (blockIdx.x * 256 + threadIdx.x) * 8;
  float4 a = *(const float4*)(x + i);
  float4 b = *(const float4*)(x + i + 4);
  short8 pk;
  pk[0] = (short)f2bf(a.x); pk[1] = (short)f2bf(a.y);
  pk[2] = (short)f2bf(a.z); pk[3] = (short)f2bf(a.w);
  pk[4] = (short)f2bf(b.x); pk[5] = (short)f2bf(b.y);
  pk[6] = (short)f2bf(b.z); pk[7] = (short)f2bf(b.w);
  *(short8*)(xh + i) = pk;
}

// ---------------- kernel 1: pool (bf16 gather) + W transpose ----------------
__global__ __launch_bounds__(256) void prep_kernel(
    const unsigned short* __restrict__ xh, const int* __restrict__ col,
    const float* __restrict__ value, const float* __restrict__ W,
    unsigned short* __restrict__ pooled, unsigned short* __restrict__ Wt) {
  int bid = blockIdx.x;
  if (bid < POOL_BLOCKS) {
    int m = bid * 8 + (threadIdx.x >> 5);        // 8 rows/block, 32 thr/row
    int t = threadIdx.x & 31;                    // 8 elems each
    int b = (unsigned)m / N_OUT;
    int n = m - b * N_OUT;
    int j = 3 * n;
    int c0 = col[j], c1 = col[j + 1], c2 = col[j + 2];
    float v0 = value[j], v1 = value[j + 1], v2 = value[j + 2];
    const short8* x0 = (const short8*)(xh + ((size_t)b * N_IN + c0) * D_IN);
    const short8* x1 = (const short8*)(xh + ((size_t)b * N_IN + c1) * D_IN);
    const short8* x2 = (const short8*)(xh + ((size_t)b * N_IN + c2) * D_IN);
    short8 a0 = x0[t], a1 = x1[t], a2 = x2[t];
    short8 pk;
    #pragma unroll
    for (int e = 0; e < 8; ++e) {
      float f = v0 * bf2f((unsigned short)a0[e]) +
                v1 * bf2f((unsigned short)a1[e]) +
                v2 * bf2f((unsigned short)a2[e]);
      pk[e] = (short)f2bf(f);
    }
    ((short8*)(pooled + (size_t)m * D_IN))[t] = pk;
  } else {
    int idx = (bid - POOL_BLOCKS) * 256 + threadIdx.x;  // over 128*2304
    int o = idx / KTOT, k = idx - o * KTOT;
    Wt[idx] = f2bf(W[(size_t)k * D_OUTC + o]);
  }
}

// ---------------- kernel 2: gather-GEMM, BM=256, counted-vmcnt pipeline -----
// 512 thr = 8 waves (4x2 of 64x64); 16x16x32 MFMA. LDS: A 2x32KB + B 2x16KB.
// Schedule per phase p: stage(p+1) -> vmcnt(6) [stage(p) landed, stage(p+1)
// stays in flight] -> s_barrier -> compute(p) -> s_barrier [buf p free].
__global__ __launch_bounds__(512, 2) void gemm_kernel(
    const unsigned short* __restrict__ pooled,   // bf16 bits [MM][256]
    const unsigned short* __restrict__ Wt,       // bf16 bits [128][2304]
    const int* __restrict__ indices,
    const float* __restrict__ bias,
    float* __restrict__ out) {
  __shared__ unsigned short Asm[2][BM * BK];     // 2 x 32 KB
  __shared__ unsigned short Bsm[2][D_OUTC * BK]; // 2 x 16 KB

  const int tid = threadIdx.x;
  const int wave = tid >> 6, lane = tid & 63;
  const int wr = wave >> 1, wc = wave & 1;       // 4x2 waves of 64x64

  // XCD-aware bijective swizzle (NWG=195: q8=24, r8=3)
  const int xcd = blockIdx.x & 7, loc = blockIdx.x >> 3;
  const int q8 = NWG >> 3, r8 = NWG & 7;
  const int wg = (xcd < r8 ? xcd * (q8 + 1) : r8 * (q8 + 1) + (xcd - r8) * q8) + loc;
  const int bm = wg * BM;

  // staging geometry: srow = tid>>3 (0..63), chunk = tid&7 of 8x16B/row.
  // A: 4 instrs, rows r = i*64+srow; B: 2 instrs, rows o = i*64+srow.
  const int srow = tid >> 3;
  const int sc = ((tid & 7) ^ (srow & 7)) * 8;   // XOR-swizzled source chunk
  int nn[4]; size_t gb[4];
  #pragma unroll
  for (int i = 0; i < 4; ++i) {
    int r = i * 64 + srow;                       // 0..255
    int m = bm + r; if (m >= MM) m = MM - 1;     // tail clamp (stores guarded)
    int b = (unsigned)m / N_OUT;
    nn[i] = m - b * N_OUT;
    gb[i] = (size_t)b * N_OUT;
  }
  const unsigned short* wtrow[2];
  #pragma unroll
  for (int i = 0; i < 2; ++i)
    wtrow[i] = Wt + (size_t)(i * 64 + srow) * KTOT + sc;
  char* AsmB = (char*)&Asm[0][0];
  char* BsmB = (char*)&Bsm[0][0];

  // spiral gather indices, current + next
  int gc[4], gn[4];
  #pragma unroll
  for (int i = 0; i < 4; ++i) gc[i] = indices[nn[i] * NS + 0];

  f32x4 acc[4][4];
  #pragma unroll
  for (int i = 0; i < 4; ++i)
    #pragma unroll
    for (int j = 0; j < 4; ++j) acc[i][j] = f32x4{0.f, 0.f, 0.f, 0.f};

  // stage phase (s,q) into buffer buf: 6 vmem instrs per wave (4A + 2B)
  auto stage = [&](int buf, int s, int q, const int* g) {
    const int kq = s * 256 + q * 64;
    #pragma unroll
    for (int i = 0; i < 4; ++i) {
      const unsigned short* srcA =
          pooled + (((gb[i] + (size_t)g[i]) << 8) + q * 64 + sc);
      gload16(srcA, AsmB + buf * 32768 + i * 8192 + tid * 16);
    }
    #pragma unroll
    for (int i = 0; i < 2; ++i)
      gload16(wtrow[i] + kq, BsmB + buf * 16384 + i * 8192 + tid * 16);
  };

  auto compute = [&](int buf) {
    const char* Ab = AsmB + buf * 32768;
    const char* Bb = BsmB + buf * 16384;
    #pragma unroll
    for (int h = 0; h < 2; ++h) {
      short8 af[4], bf[4];
      const int cb = h * 64 + (lane >> 4) * 16;  // byte col within 128B row
      #pragma unroll
      for (int i = 0; i < 4; ++i) {
        int r = wr * 64 + i * 16 + (lane & 15);
        af[i] = *(const short8*)(Ab + r * 128 + (cb ^ ((r & 7) << 4)));
      }
      #pragma unroll
      for (int j = 0; j < 4; ++j) {
        int o = wc * 64 + j * 16 + (lane & 15);
        bf[j] = *(const short8*)(Bb + o * 128 + (cb ^ ((o & 7) << 4)));
      }
      __builtin_amdgcn_s_setprio(1);
      #pragma unroll
      for (int i = 0; i < 4; ++i)
        #pragma unroll
        for (int j = 0; j < 4; ++j)
          acc[i][j] = __builtin_amdgcn_mfma_f32_16x16x32_bf16(
              af[i], bf[j], acc[i][j], 0, 0, 0);
      __builtin_amdgcn_s_setprio(0);
    }
  };

#define WAITV6() asm volatile("s_waitcnt vmcnt(6)" ::: "memory")
#define WAITV0() asm volatile("s_waitcnt vmcnt(0)" ::: "memory")
#define BAR()    __builtin_amdgcn_s_barrier()
#define FENCE()  asm volatile("" ::: "memory")

  // ---- counted-vmcnt pipeline over 36 phases -------------------------------
  stage(0, 0, 0, gc);
  FENCE();

  for (int s = 0; s < NS; ++s) {
    #pragma unroll
    for (int q = 0; q < 4; ++q) {
      const int buf = (s * 4 + q) & 1;
      if (q == 0 && s < NS - 1) {
        // index prefetch issued BEFORE stage(p+1): retired by the vmcnt(6)
        #pragma unroll
        for (int i = 0; i < 4; ++i) gn[i] = indices[nn[i] * NS + s + 1];
        FENCE();
      }
      if (q < 3)            stage(buf ^ 1, s, q + 1, gc);
      else if (s < NS - 1)  stage(buf ^ 1, s + 1, 0, gn);
      FENCE();
      if (s == NS - 1 && q == 3) { WAITV0(); } else { WAITV6(); }
      BAR();                 // stage(p) landed for every wave
      FENCE();
      compute(buf);
      FENCE();
      BAR();                 // all waves done reading buf p -> reusable
      FENCE();
    }
    #pragma unroll
    for (int i = 0; i < 4; ++i) gc[i] = gn[i];
  }

#undef WAITV6
#undef WAITV0
#undef BAR
#undef FENCE

  // ---- epilogue: bias + relu (guard tail rows) ----
  #pragma unroll
  for (int j = 0; j < 4; ++j) {
    int colo = wc * 64 + j * 16 + (lane & 15);
    float bo = bias[colo];
    #pragma unroll
    for (int i = 0; i < 4; ++i) {
      int rb = bm + wr * 64 + i * 16 + (lane >> 4) * 4;
      #pragma unroll
      for (int q = 0; q < 4; ++q) {
        int row = rb + q;
        if (row < MM) out[(size_t)row * D_OUTC + colo] = fmaxf(acc[i][j][q] + bo, 0.f);
      }
    }
  }
}

extern "C" void kernel_launch(void* const* d_in, const int* in_sizes, int n_in,
                              void* d_out, int out_size, void* d_ws, size_t ws_size,
                              hipStream_t stream) {
  const float* x       = (const float*)d_in[0];
  // d_in[1] = row (unused: structure is repeat(arange(N_out),3))
  const int*   col     = (const int*)d_in[2];
  const float* value   = (const float*)d_in[3];
  const int*   indices = (const int*)d_in[4];
  const float* W       = (const float*)d_in[5];
  const float* bias    = (const float*)d_in[6];
  float* out           = (float*)d_out;

  unsigned short* pooled = (unsigned short*)d_ws;
  unsigned short* Wt  = (unsigned short*)((char*)d_ws + (size_t)MM * D_IN * 2);
  unsigned short* xh  = (unsigned short*)((char*)d_ws + (size_t)MM * D_IN * 2
                                          + (size_t)D_OUTC * KTOT * 2);

  xcvt_kernel<<<XCVT_BLOCKS, 256, 0, stream>>>(x, xh);
  prep_kernel<<<POOL_BLOCKS + WT_BLOCKS, 256, 0, stream>>>(xh, col, value, W,
                                                           pooled, Wt);
  gemm_kernel<<<NWG, 512, 0, stream>>>(pooled, Wt, indices, bias, out);
}

// Round 11
// 69.402 us; speedup vs baseline: 1.1708x; 1.0346x over previous
//
#include <hip/hip_runtime.h>
#include <hip/hip_bf16.h>
#include <stdint.h>

#define N_IN 195
#define N_OUT 778
#define D_IN 256
#define D_OUTC 128
#define NS 9
#define KTOT 2304          // NS * D_IN
#define MM 49792           // 64 * 778
#define BM 256
#define BK 64
#define NWG 195            // ceil(MM/256); last tile half-padded
#define XE 3194880         // x elems = 64*195*256
#define XCVT_BLOCKS 1560   // XE / (256*8)
#define POOL_BLOCKS 6224   // MM / 8
#define WT_BLOCKS 1152     // 128*2304/256

using short8  = __attribute__((ext_vector_type(8))) short;
using f32x4   = __attribute__((ext_vector_type(4))) float;

__device__ __forceinline__ void gload16(const void* g, void* l) {
  __builtin_amdgcn_global_load_lds(
      (const __attribute__((address_space(1))) uint32_t*)g,
      (__attribute__((address_space(3))) uint32_t*)l, 16, 0, 0);
}

__device__ __forceinline__ unsigned short f2bf(float f) {  // RNE
  uint32_t u = __float_as_uint(f);
  return (unsigned short)((u + 0x7FFFu + ((u >> 16) & 1u)) >> 16);
}
__device__ __forceinline__ float bf2f(unsigned short s) {
  return __uint_as_float(((uint32_t)s) << 16);
}

// ---------------- kernel 0: x -> bf16 ---------------------------------------
__global__ __launch_bounds__(256) void xcvt_kernel(
    const float* __restrict__ x, unsigned short* __restrict__ xh) {
  int i = (blockIdx.x * 256 + threadIdx.x) * 8;
  float4 a = *(const float4*)(x + i);
  float4 b = *(const float4*)(x + i + 4);
  short8 pk;
  pk[0] = (short)f2bf(a.x); pk[1] = (short)f2bf(a.y);
  pk[2] = (short)f2bf(a.z); pk[3] = (short)f2bf(a.w);
  pk[4] = (short)f2bf(b.x); pk[5] = (short)f2bf(b.y);
  pk[6] = (short)f2bf(b.z); pk[7] = (short)f2bf(b.w);
  *(short8*)(xh + i) = pk;
}

// ---------------- kernel 1: pool (bf16 gather) + W transpose ----------------
__global__ __launch_bounds__(256) void prep_kernel(
    const unsigned short* __restrict__ xh, const int* __restrict__ col,
    const float* __restrict__ value, const float* __restrict__ W,
    unsigned short* __restrict__ pooled, unsigned short* __restrict__ Wt) {
  int bid = blockIdx.x;
  if (bid < POOL_BLOCKS) {
    int m = bid * 8 + (threadIdx.x >> 5);        // 8 rows/block, 32 thr/row
    int t = threadIdx.x & 31;                    // 8 elems each
    int b = (unsigned)m / N_OUT;
    int n = m - b * N_OUT;
    int j = 3 * n;
    int c0 = col[j], c1 = col[j + 1], c2 = col[j + 2];
    float v0 = value[j], v1 = value[j + 1], v2 = value[j + 2];
    const short8* x0 = (const short8*)(xh + ((size_t)b * N_IN + c0) * D_IN);
    const short8* x1 = (const short8*)(xh + ((size_t)b * N_IN + c1) * D_IN);
    const short8* x2 = (const short8*)(xh + ((size_t)b * N_IN + c2) * D_IN);
    short8 a0 = x0[t], a1 = x1[t], a2 = x2[t];
    short8 pk;
    #pragma unroll
    for (int e = 0; e < 8; ++e) {
      float f = v0 * bf2f((unsigned short)a0[e]) +
                v1 * bf2f((unsigned short)a1[e]) +
                v2 * bf2f((unsigned short)a2[e]);
      pk[e] = (short)f2bf(f);
    }
    ((short8*)(pooled + (size_t)m * D_IN))[t] = pk;
  } else {
    int idx = (bid - POOL_BLOCKS) * 256 + threadIdx.x;  // over 128*2304
    int o = idx / KTOT, k = idx - o * KTOT;
    Wt[idx] = f2bf(W[(size_t)k * D_OUTC + o]);
  }
}

// ---------------- kernel 2: gather-GEMM, BM=256, 16 waves, 3-buf 2-deep -----
// 1024 thr = 16 waves (4 row-groups x 4 col-groups); wave tile 64x32
// (4x2 frags of 16x16), 16x16x32 MFMA. LDS: A 3x32KB + B 3x16KB = 144 KB.
// Schedule per phase p: stage(p+2) -> vmcnt(6) [stage(p) landed; p+1,p+2 in
// flight] -> s_barrier -> compute(p) -> s_barrier. Reuse distance 3 > skew 1.
__global__ __launch_bounds__(1024, 1) void gemm_kernel(
    const unsigned short* __restrict__ pooled,   // bf16 bits [MM][256]
    const unsigned short* __restrict__ Wt,       // bf16 bits [128][2304]
    const int* __restrict__ indices,
    const float* __restrict__ bias,
    float* __restrict__ out) {
  __shared__ unsigned short Asm[3][BM * BK];     // 3 x 32 KB
  __shared__ unsigned short Bsm[3][D_OUTC * BK]; // 3 x 16 KB

  const int tid = threadIdx.x;
  const int wave = tid >> 6, lane = tid & 63;
  const int wr = wave >> 2, wc = wave & 3;       // 4x4 waves of 64x32

  // XCD-aware bijective swizzle (NWG=195: q8=24, r8=3)
  const int xcd = blockIdx.x & 7, loc = blockIdx.x >> 3;
  const int q8 = NWG >> 3, r8 = NWG & 7;
  const int wg = (xcd < r8 ? xcd * (q8 + 1) : r8 * (q8 + 1) + (xcd - r8) * q8) + loc;
  const int bm = wg * BM;

  // staging: srow = tid>>3 (0..127), chunk = tid&7 of 8x16B per 128B row.
  // A: 2 instrs, rows r = i*128+srow; B: 1 instr, row o = srow.
  const int srow = tid >> 3;
  const int sc = ((tid & 7) ^ (srow & 7)) * 8;   // XOR-swizzled source chunk
  int nn[2]; size_t gb[2];
  #pragma unroll
  for (int i = 0; i < 2; ++i) {
    int r = i * 128 + srow;                      // 0..255
    int m = bm + r; if (m >= MM) m = MM - 1;     // tail clamp (stores guarded)
    int b = (unsigned)m / N_OUT;
    nn[i] = m - b * N_OUT;
    gb[i] = (size_t)b * N_OUT;
  }
  const unsigned short* wtrow = Wt + (size_t)srow * KTOT + sc;
  char* AsmB = (char*)&Asm[0][0];
  char* BsmB = (char*)&Bsm[0][0];

  // spiral gather indices, current + next
  int gc[2], gn[2];
  #pragma unroll
  for (int i = 0; i < 2; ++i) gc[i] = indices[nn[i] * NS + 0];

  f32x4 acc[4][2];
  #pragma unroll
  for (int i = 0; i < 4; ++i)
    #pragma unroll
    for (int j = 0; j < 2; ++j) acc[i][j] = f32x4{0.f, 0.f, 0.f, 0.f};

  // stage phase (s,q) into buffer buf: 3 vmem instrs per thread (2A + 1B)
  auto stage = [&](int buf, int s, int q, const int* g) {
    const int kq = s * 256 + q * 64;
    #pragma unroll
    for (int i = 0; i < 2; ++i) {
      const unsigned short* srcA =
          pooled + (((gb[i] + (size_t)g[i]) << 8) + q * 64 + sc);
      gload16(srcA, AsmB + buf * 32768 + i * 16384 + tid * 16);
    }
    gload16(wtrow + kq, BsmB + buf * 16384 + tid * 16);
  };

  auto compute = [&](int buf) {
    const char* Ab = AsmB + buf * 32768;
    const char* Bb = BsmB + buf * 16384;
    #pragma unroll
    for (int h = 0; h < 2; ++h) {
      short8 af[4], bf[2];
      const int cb = h * 64 + (lane >> 4) * 16;  // byte col within 128B row
      #pragma unroll
      for (int i = 0; i < 4; ++i) {
        int r = wr * 64 + i * 16 + (lane & 15);
        af[i] = *(const short8*)(Ab + r * 128 + (cb ^ ((r & 7) << 4)));
      }
      #pragma unroll
      for (int j = 0; j < 2; ++j) {
        int o = wc * 32 + j * 16 + (lane & 15);
        bf[j] = *(const short8*)(Bb + o * 128 + (cb ^ ((o & 7) << 4)));
      }
      __builtin_amdgcn_s_setprio(1);
      #pragma unroll
      for (int i = 0; i < 4; ++i)
        #pragma unroll
        for (int j = 0; j < 2; ++j)
          acc[i][j] = __builtin_amdgcn_mfma_f32_16x16x32_bf16(
              af[i], bf[j], acc[i][j], 0, 0, 0);
      __builtin_amdgcn_s_setprio(0);
    }
  };

#define WAITV8() asm volatile("s_waitcnt vmcnt(8)" ::: "memory")
#define WAITV6() asm volatile("s_waitcnt vmcnt(6)" ::: "memory")
#define WAITV3() asm volatile("s_waitcnt vmcnt(3)" ::: "memory")
#define WAITV0() asm volatile("s_waitcnt vmcnt(0)" ::: "memory")
#define BAR()    __builtin_amdgcn_s_barrier()
#define FENCE()  asm volatile("" ::: "memory")

  // ---- prologue: phases 0,1 in flight ---------------------------------------
  stage(0, 0, 0, gc); FENCE();
  stage(1, 0, 1, gc); FENCE();

  int bc = 0;  // buffer of the phase being computed
  for (int s = 0; s < 8; ++s) {
    #pragma unroll
    for (int q = 0; q < 4; ++q) {
      const int bs = bc == 0 ? 2 : bc - 1;       // (bc+2) % 3
      if (q < 2) stage(bs, s, q + 2, gc);
      else       stage(bs, s + 1, q - 2, gn);
      FENCE();
      if (q == 0) {
        // next-spiral index prefetch AFTER the stage: vmcnt(8) still retires
        // exactly stage(p); gn retired by dependency wait before its use.
        #pragma unroll
        for (int i = 0; i < 2; ++i) gn[i] = indices[nn[i] * NS + s + 1];
        FENCE();
        WAITV8();
      } else {
        WAITV6();
      }
      BAR(); FENCE();
      compute(bc);
      FENCE(); BAR();
      bc = bc == 2 ? 0 : bc + 1;
    }
    #pragma unroll
    for (int i = 0; i < 2; ++i) gc[i] = gn[i];
  }
  // ---- spiral 8 tail (phases 32..35; stages 34,35 then drain) ---------------
  {
    int bs = bc == 0 ? 2 : bc - 1;
    stage(bs, 8, 2, gc); FENCE();
    WAITV6(); BAR(); FENCE(); compute(bc); FENCE(); BAR();
    bc = bc == 2 ? 0 : bc + 1;

    bs = bc == 0 ? 2 : bc - 1;
    stage(bs, 8, 3, gc); FENCE();
    WAITV6(); BAR(); FENCE(); compute(bc); FENCE(); BAR();
    bc = bc == 2 ? 0 : bc + 1;

    WAITV3(); BAR(); FENCE(); compute(bc); FENCE(); BAR();
    bc = bc == 2 ? 0 : bc + 1;

    WAITV0(); BAR(); FENCE(); compute(bc); FENCE(); BAR();
  }

#undef WAITV8
#undef WAITV6
#undef WAITV3
#undef WAITV0
#undef BAR
#undef FENCE

  // ---- epilogue: bias + relu (guard tail rows) ----
  #pragma unroll
  for (int j = 0; j < 2; ++j) {
    int colo = wc * 32 + j * 16 + (lane & 15);
    float bo = bias[colo];
    #pragma unroll
    for (int i = 0; i < 4; ++i) {
      int rb = bm + wr * 64 + i * 16 + (lane >> 4) * 4;
      #pragma unroll
      for (int q = 0; q < 4; ++q) {
        int row = rb + q;
        if (row < MM) out[(size_t)row * D_OUTC + colo] = fmaxf(acc[i][j][q] + bo, 0.f);
      }
    }
  }
}

extern "C" void kernel_launch(void* const* d_in, const int* in_sizes, int n_in,
                              void* d_out, int out_size, void* d_ws, size_t ws_size,
                              hipStream_t stream) {
  const float* x       = (const float*)d_in[0];
  // d_in[1] = row (unused: structure is repeat(arange(N_out),3))
  const int*   col     = (const int*)d_in[2];
  const float* value   = (const float*)d_in[3];
  const int*   indices = (const int*)d_in[4];
  const float* W       = (const float*)d_in[5];
  const float* bias    = (const float*)d_in[6];
  float* out           = (float*)d_out;

  unsigned short* pooled = (unsigned short*)d_ws;
  unsigned short* Wt  = (unsigned short*)((char*)d_ws + (size_t)MM * D_IN * 2);
  unsigned short* xh  = (unsigned short*)((char*)d_ws + (size_t)MM * D_IN * 2
                                          + (size_t)D_OUTC * KTOT * 2);

  xcvt_kernel<<<XCVT_BLOCKS, 256, 0, stream>>>(x, xh);
  prep_kernel<<<POOL_BLOCKS + WT_BLOCKS, 256, 0, stream>>>(xh, col, value, W,
                                                           pooled, Wt);
  gemm_kernel<<<NWG, 1024, 0, stream>>>(pooled, Wt, indices, bias, out);
}

// Round 12
// 62.000 us; speedup vs baseline: 1.3106x; 1.1194x over previous
//
#include <hip/hip_runtime.h>
#include <hip/hip_bf16.h>
#include <stdint.h>

#define N_IN 195
#define N_OUT 778
#define D_IN 256
#define D_OUTC 128
#define NS 9
#define KTOT 2304          // NS * D_IN
#define MM 49792           // 64 * 778 = 389 * 128, no tail
#define BM 128
#define BK 64
#define NWG 389
#define XE 3194880         // x elems = 64*195*256
#define XCVT_BLOCKS 1560   // XE / (256*8)
#define POOL_BLOCKS 6224   // MM / 8
#define WT_BLOCKS 1152     // 128*2304/256

using short8  = __attribute__((ext_vector_type(8))) short;
using f32x4   = __attribute__((ext_vector_type(4))) float;

__device__ __forceinline__ void gload16(const void* g, void* l) {
  __builtin_amdgcn_global_load_lds(
      (const __attribute__((address_space(1))) uint32_t*)g,
      (__attribute__((address_space(3))) uint32_t*)l, 16, 0, 0);
}

__device__ __forceinline__ unsigned short f2bf(float f) {  // RNE
  uint32_t u = __float_as_uint(f);
  return (unsigned short)((u + 0x7FFFu + ((u >> 16) & 1u)) >> 16);
}
__device__ __forceinline__ float bf2f(unsigned short s) {
  return __uint_as_float(((uint32_t)s) << 16);
}

// ---------------- kernel 0: x -> bf16 ---------------------------------------
__global__ __launch_bounds__(256) void xcvt_kernel(
    const float* __restrict__ x, unsigned short* __restrict__ xh) {
  int i = (blockIdx.x * 256 + threadIdx.x) * 8;
  float4 a = *(const float4*)(x + i);
  float4 b = *(const float4*)(x + i + 4);
  short8 pk;
  pk[0] = (short)f2bf(a.x); pk[1] = (short)f2bf(a.y);
  pk[2] = (short)f2bf(a.z); pk[3] = (short)f2bf(a.w);
  pk[4] = (short)f2bf(b.x); pk[5] = (short)f2bf(b.y);
  pk[6] = (short)f2bf(b.z); pk[7] = (short)f2bf(b.w);
  *(short8*)(xh + i) = pk;
}

// ---------------- kernel 1: pool (bf16 gather) + W transpose ----------------
__global__ __launch_bounds__(256) void prep_kernel(
    const unsigned short* __restrict__ xh, const int* __restrict__ col,
    const float* __restrict__ value, const float* __restrict__ W,
    unsigned short* __restrict__ pooled, unsigned short* __restrict__ Wt) {
  int bid = blockIdx.x;
  if (bid < POOL_BLOCKS) {
    int m = bid * 8 + (threadIdx.x >> 5);        // 8 rows/block, 32 thr/row
    int t = threadIdx.x & 31;                    // 8 elems each
    int b = (unsigned)m / N_OUT;
    int n = m - b * N_OUT;
    int j = 3 * n;
    int c0 = col[j], c1 = col[j + 1], c2 = col[j + 2];
    float v0 = value[j], v1 = value[j + 1], v2 = value[j + 2];
    const short8* x0 = (const short8*)(xh + ((size_t)b * N_IN + c0) * D_IN);
    const short8* x1 = (const short8*)(xh + ((size_t)b * N_IN + c1) * D_IN);
    const short8* x2 = (const short8*)(xh + ((size_t)b * N_IN + c2) * D_IN);
    short8 a0 = x0[t], a1 = x1[t], a2 = x2[t];
    short8 pk;
    #pragma unroll
    for (int e = 0; e < 8; ++e) {
      float f = v0 * bf2f((unsigned short)a0[e]) +
                v1 * bf2f((unsigned short)a1[e]) +
                v2 * bf2f((unsigned short)a2[e]);
      pk[e] = (short)f2bf(f);
    }
    ((short8*)(pooled + (size_t)m * D_IN))[t] = pk;
  } else {
    int idx = (bid - POOL_BLOCKS) * 256 + threadIdx.x;  // over 128*2304
    int o = idx / KTOT, k = idx - o * KTOT;
    Wt[idx] = f2bf(W[(size_t)k * D_OUTC + o]);
  }
}

// ---------------- kernel 2: gather-GEMM, BM=128, 2 blocks/CU + counted vmcnt
// 512 thr = 8 waves (4 row-groups x 2 col-groups); wave tile 32x64
// (2x4 frags of 16x16), 16x16x32 MFMA. LDS: A 2x16KB + B 2x16KB = 64 KB
// -> 2 blocks/CU co-resident (desynced). Per phase: stage(p+1) -> vmcnt(4)
// [stage(p) landed; stage(p+1) in flight across compute] -> barrier ->
// compute(p) -> barrier (buffer reuse safe; R10-proven discipline).
__global__ __launch_bounds__(512, 4) void gemm_kernel(
    const unsigned short* __restrict__ pooled,   // bf16 bits [MM][256]
    const unsigned short* __restrict__ Wt,       // bf16 bits [128][2304]
    const int* __restrict__ indices,
    const float* __restrict__ bias,
    float* __restrict__ out) {
  __shared__ unsigned short Asm[2][BM * BK];     // 2 x 16 KB
  __shared__ unsigned short Bsm[2][D_OUTC * BK]; // 2 x 16 KB

  const int tid = threadIdx.x;
  const int wave = tid >> 6, lane = tid & 63;
  const int wr = wave >> 1, wc = wave & 1;       // 4x2 waves of 32x64

  // XCD-aware bijective swizzle (NWG=389: q8=48, r8=5)
  const int xcd = blockIdx.x & 7, loc = blockIdx.x >> 3;
  const int q8 = NWG >> 3, r8 = NWG & 7;
  const int wg = (xcd < r8 ? xcd * (q8 + 1) : r8 * (q8 + 1) + (xcd - r8) * q8) + loc;
  const int bm = wg * BM;

  // staging: srow = tid>>3 (0..63), chunk = tid&7 of 8x16B per 128B row.
  // A: 2 instrs, rows r = i*64+srow; B: 2 instrs, rows o = i*64+srow.
  const int srow = tid >> 3;
  const int sc = ((tid & 7) ^ (srow & 7)) * 8;   // XOR-swizzled source chunk
  int nn[2]; size_t gb[2];
  #pragma unroll
  for (int i = 0; i < 2; ++i) {
    int r = i * 64 + srow;                       // 0..127
    int m = bm + r;
    int b = (unsigned)m / N_OUT;
    nn[i] = m - b * N_OUT;
    gb[i] = (size_t)b * N_OUT;
  }
  const unsigned short* wtrow[2];
  #pragma unroll
  for (int i = 0; i < 2; ++i)
    wtrow[i] = Wt + (size_t)(i * 64 + srow) * KTOT + sc;
  char* AsmB = (char*)&Asm[0][0];
  char* BsmB = (char*)&Bsm[0][0];

  // spiral gather indices, current + next
  int gc[2], gn[2];
  #pragma unroll
  for (int i = 0; i < 2; ++i) gc[i] = indices[nn[i] * NS + 0];

  f32x4 acc[2][4];
  #pragma unroll
  for (int i = 0; i < 2; ++i)
    #pragma unroll
    for (int j = 0; j < 4; ++j) acc[i][j] = f32x4{0.f, 0.f, 0.f, 0.f};

  // stage phase (s,q) into buffer buf: 4 vmem instrs per thread (2A + 2B)
  auto stage = [&](int buf, int s, int q, const int* g) {
    const int kq = s * 256 + q * 64;
    #pragma unroll
    for (int i = 0; i < 2; ++i) {
      const unsigned short* srcA =
          pooled + (((gb[i] + (size_t)g[i]) << 8) + q * 64 + sc);
      gload16(srcA, AsmB + buf * 16384 + i * 8192 + tid * 16);
    }
    #pragma unroll
    for (int i = 0; i < 2; ++i)
      gload16(wtrow[i] + kq, BsmB + buf * 16384 + i * 8192 + tid * 16);
  };

  auto compute = [&](int buf) {
    const char* Ab = AsmB + buf * 16384;
    const char* Bb = BsmB + buf * 16384;
    #pragma unroll
    for (int h = 0; h < 2; ++h) {
      short8 af[2], bf[4];
      const int cb = h * 64 + (lane >> 4) * 16;  // byte col within 128B row
      #pragma unroll
      for (int i = 0; i < 2; ++i) {
        int r = wr * 32 + i * 16 + (lane & 15);
        af[i] = *(const short8*)(Ab + r * 128 + (cb ^ ((r & 7) << 4)));
      }
      #pragma unroll
      for (int j = 0; j < 4; ++j) {
        int o = wc * 64 + j * 16 + (lane & 15);
        bf[j] = *(const short8*)(Bb + o * 128 + (cb ^ ((o & 7) << 4)));
      }
      __builtin_amdgcn_s_setprio(1);
      #pragma unroll
      for (int i = 0; i < 2; ++i)
        #pragma unroll
        for (int j = 0; j < 4; ++j)
          acc[i][j] = __builtin_amdgcn_mfma_f32_16x16x32_bf16(
              af[i], bf[j], acc[i][j], 0, 0, 0);
      __builtin_amdgcn_s_setprio(0);
    }
  };

#define WAITV6() asm volatile("s_waitcnt vmcnt(6)" ::: "memory")
#define WAITV4() asm volatile("s_waitcnt vmcnt(4)" ::: "memory")
#define WAITV0() asm volatile("s_waitcnt vmcnt(0)" ::: "memory")
#define BAR()    __builtin_amdgcn_s_barrier()
#define FENCE()  asm volatile("" ::: "memory")

  // ---- counted-vmcnt pipeline over 36 phases -------------------------------
  stage(0, 0, 0, gc);
  FENCE();

  for (int s = 0; s < NS; ++s) {
    #pragma unroll
    for (int q = 0; q < 4; ++q) {
      const int buf = (s * 4 + q) & 1;
      const bool last = (s == NS - 1) && (q == 3);
      if (!last) {
        if (q < 3) stage(buf ^ 1, s, q + 1, gc);
        else       stage(buf ^ 1, s + 1, 0, gn);
        FENCE();
      }
      if (q == 0 && s < NS - 1) {
        // index prefetch issued AFTER stage(p+1): vmcnt(6) retires stage(p),
        // keeps stage(p+1)+gn in flight; gn retired by later waits.
        #pragma unroll
        for (int i = 0; i < 2; ++i) gn[i] = indices[nn[i] * NS + s + 1];
        FENCE();
        WAITV6();
      } else if (last) {
        WAITV0();
      } else {
        WAITV4();
      }
      BAR(); FENCE();
      compute(buf);
      FENCE(); BAR();
    }
    if (s < NS - 1) {
      #pragma unroll
      for (int i = 0; i < 2; ++i) gc[i] = gn[i];
    }
  }

#undef WAITV6
#undef WAITV4
#undef WAITV0
#undef BAR
#undef FENCE

  // ---- epilogue: bias + relu ----
  #pragma unroll
  for (int j = 0; j < 4; ++j) {
    int colo = wc * 64 + j * 16 + (lane & 15);
    float bo = bias[colo];
    #pragma unroll
    for (int i = 0; i < 2; ++i) {
      int rb = bm + wr * 32 + i * 16 + (lane >> 4) * 4;
      #pragma unroll
      for (int q = 0; q < 4; ++q) {
        int row = rb + q;
        out[(size_t)row * D_OUTC + colo] = fmaxf(acc[i][j][q] + bo, 0.f);
      }
    }
  }
}

extern "C" void kernel_launch(void* const* d_in, const int* in_sizes, int n_in,
                              void* d_out, int out_size, void* d_ws, size_t ws_size,
                              hipStream_t stream) {
  const float* x       = (const float*)d_in[0];
  // d_in[1] = row (unused: structure is repeat(arange(N_out),3))
  const int*   col     = (const int*)d_in[2];
  const float* value   = (const float*)d_in[3];
  const int*   indices = (const int*)d_in[4];
  const float* W       = (const float*)d_in[5];
  const float* bias    = (const float*)d_in[6];
  float* out           = (float*)d_out;

  unsigned short* pooled = (unsigned short*)d_ws;
  unsigned short* Wt  = (unsigned short*)((char*)d_ws + (size_t)MM * D_IN * 2);
  unsigned short* xh  = (unsigned short*)((char*)d_ws + (size_t)MM * D_IN * 2
                                          + (size_t)D_OUTC * KTOT * 2);

  xcvt_kernel<<<XCVT_BLOCKS, 256, 0, stream>>>(x, xh);
  prep_kernel<<<POOL_BLOCKS + WT_BLOCKS, 256, 0, stream>>>(xh, col, value, W,
                                                           pooled, Wt);
  gemm_kernel<<<NWG, 512, 0, stream>>>(pooled, Wt, indices, bias, out);
}